// Round 13
// baseline (569.268 us; speedup 1.0000x reference)
//
#include <hip/hip_runtime.h>
#include <hip/hip_fp16.h>

// DKVMN forward, v13 — forced v_pk_fma_f16 probe (single variable vs v12).
//  R12 post-mortem: f16 via __hfma2 cut issue only 4% (255us vs 266) — either
//  the compiler scalarized it, or CDNA4 VOP3P is half-rate/elem (consistent
//  with R6's pk-f32 neutrality). v13 forces v_pk_fma_f16 via inline asm on
//  u32-packed half2 regs. If issue drops to ~155us -> compiler problem, keep.
//  If unchanged -> VALU floor reached for the state recurrence.
//  R12 also validated f16-state precision (absmax unchanged at 0.0039).
//  k1 build_wq : Wt f32 row + Wh f16-pair row + Q1
//  k2 build_ea : EA[10001,200] packed bf16 {e,a} (f32 math, proven)
//  k2b pack_w1 : W1 -> bf16 MFMA B-frag order
//  k3 dkvmn_state: barrier-free recurrence, 256 thr, asm pk-f16, SGPR wrow
//      pairs, EA prefetch depth 2, writes RD bf16.
//  k4 mlp_pred : MFMA 16x16x32 bf16 GEMM [B*S,224]@[224,64] + fused epilogue.
// Workspace: Wt 1MB | Q1 1MB | EA 8MB | W1s 32KB | Wh 0.6MB | RD 164MB.

#define NQ1   5001
#define NQA   10001
#define MEMN  50
#define KD    50
#define VD    200
#define FC    50
#define BB    2048
#define SS    200
#define EA_R  16
#define WHS   28       // Wh row stride in u32 (25 pairs + 3 pad, 112B)

typedef unsigned int   u32;
typedef unsigned short u16;
typedef short  s8v  __attribute__((ext_vector_type(8)));   // 8 bf16 (4 VGPRs)
typedef float  f4v  __attribute__((ext_vector_type(4)));   // MFMA C/D

__device__ __forceinline__ float fast_sigmoid(float x) { return 1.f / (1.f + __expf(-x)); }
__device__ __forceinline__ float fast_tanh(float x) {
    float e2 = __expf(2.f * x);           // inf-safe
    return 1.f - 2.f / (e2 + 1.f);
}
__device__ __forceinline__ float bfu16_to_f(u16 u) {
    union { float f; u32 i; } x; x.i = ((u32)u) << 16; return x.f;
}
__device__ __forceinline__ u16 f_to_bfu16(float f) {   // RNE, finite inputs
    union { float f; u32 i; } x; x.f = f;
    return (u16)((x.i + 0x7fffu + ((x.i >> 16) & 1u)) >> 16);
}
__device__ __forceinline__ u32 h2_to_u32(__half2 h) {
    union { __half2 h; u32 i; } x; x.h = h; return x.i;
}
__device__ __forceinline__ __half2 u32_to_h2(u32 u) {
    union { u32 i; __half2 h; } x; x.i = u; return x.h;
}
// forced packed f16 fma: d.lo = a.lo*b.lo+c.lo ; d.hi = a.hi*b.hi+c.hi
__device__ __forceinline__ u32 pk_fma_f16(u32 a, u32 b, u32 c) {
    u32 d;
    asm("v_pk_fma_f16 %0, %1, %2, %3" : "=v"(d) : "v"(a), "v"(b), "v"(c));
    return d;
}

// ---- per-q tables: softmax row (f32 + f16-pair), q-half of MLP layer 1 ----
__global__ void build_wq(const float* __restrict__ qemb,
                         const float* __restrict__ km,
                         const float* __restrict__ w1,
                         const float* __restrict__ b1,
                         float* __restrict__ Wt, u32* __restrict__ Wh,
                         float* __restrict__ Q1) {
    const int q = blockIdx.x;
    const int f = threadIdx.x;          // one wave
    __shared__ float qrow[KD];
    if (f < KD) qrow[f] = qemb[q * KD + f];
    __syncthreads();

    float s = -1e30f;
    if (f < MEMN) {
        s = 0.f;
        #pragma unroll
        for (int k = 0; k < KD; ++k) s = fmaf(qrow[k], km[f * KD + k], s);
    }
    float mx = s;
    #pragma unroll
    for (int off = 32; off >= 1; off >>= 1) mx = fmaxf(mx, __shfl_xor(mx, off, 64));
    float e = (f < MEMN) ? __expf(s - mx) : 0.f;
    float sum = e;
    #pragma unroll
    for (int off = 32; off >= 1; off >>= 1) sum += __shfl_xor(sum, off, 64);
    float wv_ = (f < MEMN) ? (e / sum) : 0.f;
    if (f < MEMN) Wt[q * MEMN + f] = wv_;

    // f16-pair row: lane i<25 packs (w[2i], w[2i+1])
    float plo = __shfl(wv_, 2 * (f & 31), 64);
    float phi = __shfl(wv_, 2 * (f & 31) + 1, 64);
    if (f < 25) {
        union { __half h; u16 u; } lo, hi;
        lo.h = __float2half(plo); hi.h = __float2half(phi);
        Wh[q * WHS + f] = (u32)lo.u | ((u32)hi.u << 16);
    } else if (f < WHS) {
        Wh[q * WHS + f] = 0;
    }

    if (f < FC) {
        float h = b1[f];
        #pragma unroll
        for (int k = 0; k < KD; ++k)
            h = fmaf(qrow[k], w1[(VD + k) * FC + f], h);
        Q1[q * FC + f] = h;
    }
}

// ---- per-qa table, packed {e,a} bf16 (f32 math — protocol-proven) ----
__global__ void build_ea(const float* __restrict__ qaemb,
                         const float* __restrict__ ew,
                         const float* __restrict__ ebias,
                         const float* __restrict__ aw,
                         const float* __restrict__ abias,
                         u32* __restrict__ EA) {
    __shared__ float qT[VD][EA_R];
    const int tid = threadIdx.x;
    const int r0 = blockIdx.x * EA_R;
    if (tid < VD) {
        #pragma unroll
        for (int r = 0; r < EA_R; ++r) {
            int row = r0 + r;
            qT[tid][r] = (row < NQA) ? qaemb[(size_t)row * VD + tid] : 0.f;
        }
    }
    __syncthreads();
    if (tid >= VD) return;

    float accE[EA_R], accA[EA_R];
    #pragma unroll
    for (int r = 0; r < EA_R; ++r) { accE[r] = 0.f; accA[r] = 0.f; }
    for (int k = 0; k < VD; ++k) {
        float we = ew[k * VD + tid];
        float wa = aw[k * VD + tid];
        #pragma unroll
        for (int r = 0; r < EA_R; ++r) {
            float qv = qT[k][r];
            accE[r] = fmaf(qv, we, accE[r]);
            accA[r] = fmaf(qv, wa, accA[r]);
        }
    }
    float be = ebias[tid], ba = abias[tid];
    #pragma unroll
    for (int r = 0; r < EA_R; ++r) {
        int row = r0 + r;
        if (row < NQA) {
            u16 e16 = f_to_bfu16(fast_sigmoid(accE[r] + be));
            u16 a16 = f_to_bfu16(fast_tanh(accA[r] + ba));
            EA[(size_t)row * VD + tid] = (u32)e16 | ((u32)a16 << 16);
        }
    }
}

// ---- W1 -> bf16 MFMA B-fragment order ----
__global__ void pack_w1(const float* __restrict__ w1, u16* __restrict__ W1s) {
    for (int idx = blockIdx.x * blockDim.x + threadIdx.x; idx < 4 * 7 * 64 * 8;
         idx += gridDim.x * blockDim.x) {
        int j    = idx & 7;
        int lane = (idx >> 3) & 63;
        int kt   = (idx >> 9) % 7;
        int nt   = idx / 3584;
        int k = kt * 32 + ((lane >> 4) << 3) + j;
        int n = nt * 16 + (lane & 15);
        float v = (k < VD && n < FC) ? w1[k * FC + n] : 0.f;
        W1s[idx] = f_to_bfu16(v);
    }
}

// ---- recurrence: 256 thr, forced pk-f16 asm, SGPR w pairs, EA depth-2 ----
__global__ __launch_bounds__(256) void dkvmn_state(
        const int* __restrict__ qd, const int* __restrict__ qad,
        const u32* __restrict__ Wh, const u32* __restrict__ EA,
        const float* __restrict__ ivm, u16* __restrict__ READ) {
    const int tid = threadIdx.x;
    const int b   = blockIdx.x;
    const int v   = tid;                         // 0..255, active if < VD
    const bool active = v < VD;
    const int vc = active ? v : VD - 1;

    u32 mv[25];                                  // pair i = slots (2i, 2i+1)
    #pragma unroll
    for (int i = 0; i < 25; ++i)
        mv[i] = h2_to_u32(__floats2half2_rn(ivm[(2 * i) * VD + vc],
                                            ivm[(2 * i + 1) * VD + vc]));

    const int base = b * SS;
    int q_c = __builtin_amdgcn_readfirstlane(qd[base]);
    int q_n = __builtin_amdgcn_readfirstlane(qd[base + 1]);
    int qa0 = __builtin_amdgcn_readfirstlane(qad[base]);
    int qa1 = __builtin_amdgcn_readfirstlane(qad[base + 1]);
    u32 ea_c = EA[(size_t)qa0 * VD + vc];
    u32 ea_n = EA[(size_t)qa1 * VD + vc];

    for (int t = 0; t < SS; ++t) {
        // prefetch step t+2 (clamped index; duplicate load harmless)
        int tn = t + 2; tn = (tn < SS) ? tn : (SS - 1);
        int q_nn  = __builtin_amdgcn_readfirstlane(qd[base + tn]);
        int qa_nn = __builtin_amdgcn_readfirstlane(qad[base + tn]);
        u32 ea_nn = EA[(size_t)qa_nn * VD + vc];

        const u32* wrow = Wh + q_c * WHS;        // uniform -> s_load clause
        float ev = bfu16_to_f((u16)(ea_c & 0xffffu));
        float av = bfu16_to_f((u16)(ea_c >> 16));
        u32 av2  = h2_to_u32(__float2half2_rn(av));
        u32 nev2 = h2_to_u32(__float2half2_rn(-ev));

        u32 rdA = 0u, rdB = 0u;                  // packed f16 zeros
        #pragma unroll
        for (int i = 0; i < 25; i += 2) {        // 13 iters (i=24 single)
            u32 w0 = wrow[i];
            rdA = pk_fma_f16(w0, mv[i], rdA);
            mv[i] = pk_fma_f16(w0, pk_fma_f16(nev2, mv[i], av2), mv[i]);
            if (i + 1 < 25) {
                u32 w1p = wrow[i + 1];
                rdB = pk_fma_f16(w1p, mv[i + 1], rdB);
                mv[i + 1] = pk_fma_f16(w1p, pk_fma_f16(nev2, mv[i + 1], av2), mv[i + 1]);
            }
        }
        if (active) {
            __half2 ra = u32_to_h2(rdA), rb = u32_to_h2(rdB);
            float rd = (__half2float(__low2half(ra)) + __half2float(__high2half(ra)))
                     + (__half2float(__low2half(rb)) + __half2float(__high2half(rb)));
            READ[(size_t)(base + t) * VD + v] = f_to_bfu16(rd);
        }
        q_c = q_n; q_n = q_nn; ea_c = ea_n; ea_n = ea_nn;
    }
}

// ---- prediction MLP via MFMA: per wave one 16-row strip, K=224, N=64 ----
__global__ __launch_bounds__(256) void mlp_pred(
        const u16* __restrict__ RD, const int* __restrict__ qd,
        const float* __restrict__ Q1tab, const u16* __restrict__ W1s,
        const float* __restrict__ w2, const float* __restrict__ b2,
        float* __restrict__ out) {
    const int tid  = threadIdx.x;
    const int lane = tid & 63;
    const int wv   = tid >> 6;
    const int strip = blockIdx.x * 4 + wv;
    const int row0  = strip * 16;

    const int mrow = lane & 15;        // A row within strip / C-D col (feature)
    const int quad = lane >> 4;

    s8v a[7];
    {
        const u16* arow = RD + (size_t)(row0 + mrow) * VD + quad * 8;
        #pragma unroll
        for (int kt = 0; kt < 7; ++kt)
            a[kt] = *(const s8v*)(arow + kt * 32);   // k>=200 garbage * B=0
    }

    const float b2f = b2[0];
    float pf[4] = {0.f, 0.f, 0.f, 0.f};

    #pragma unroll
    for (int nt = 0; nt < 4; ++nt) {
        s8v bfr[7];
        #pragma unroll
        for (int kt = 0; kt < 7; ++kt)
            bfr[kt] = *(const s8v*)(W1s + (((nt * 7 + kt) * 64) + lane) * 8);

        f4v acc = {0.f, 0.f, 0.f, 0.f};
        #pragma unroll
        for (int kt = 0; kt < 7; ++kt)
            acc = __builtin_amdgcn_mfma_f32_16x16x32_bf16(a[kt], bfr[kt], acc, 0, 0, 0);

        const int f = nt * 16 + mrow;                  // output feature col
        const float w2f = (f < FC) ? w2[f] : 0.f;
        #pragma unroll
        for (int r = 0; r < 4; ++r) {
            int row = row0 + quad * 4 + r;
            float h = acc[r] + Q1tab[qd[row] * FC + f];
            pf[r] = fmaf(fast_tanh(h), w2f, pf[r]);
        }
    }

    #pragma unroll
    for (int r = 0; r < 4; ++r) {
        float s = pf[r];
        s += __shfl_xor(s, 1, 64);
        s += __shfl_xor(s, 2, 64);
        s += __shfl_xor(s, 4, 64);
        s += __shfl_xor(s, 8, 64);
        if (mrow == 0)
            out[row0 + quad * 4 + r] = fast_sigmoid(s + b2f);
    }
}

// ---- fallback (barrier version, f32) if workspace too small ----
__global__ void dkvmn_main(const int* __restrict__ qd, const int* __restrict__ qad,
                           const float* __restrict__ Wtab, const float* __restrict__ Q1tab,
                           const u32* __restrict__ EA,
                           const float* __restrict__ ivm,
                           const float* __restrict__ w1,
                           const float* __restrict__ w2,
                           const float* __restrict__ b2,
                           float* __restrict__ out) {
    const int tid  = threadIdx.x;
    const int b    = blockIdx.x;
    const int v    = tid;
    const int lane = tid & 63;
    const int wv   = tid >> 6;

    __shared__ alignas(16) float read_lds[4 * 52];
    __shared__ alignas(16) float part_lds[4 * 52];

    float mv[MEMN];
    if (v < VD) {
        #pragma unroll
        for (int m = 0; m < MEMN; ++m) mv[m] = ivm[m * VD + v];
    }
    float w1r[50];
    if (lane < FC) {
        #pragma unroll
        for (int i = 0; i < 50; ++i) w1r[i] = w1[(wv * 50 + i) * FC + lane];
    } else {
        #pragma unroll
        for (int i = 0; i < 50; ++i) w1r[i] = 0.f;
    }
    const float w2f = (tid < FC) ? w2[tid] : 0.f;
    const float b2f = b2[0];

    const int* qrow_i  = qd  + b * SS;
    const int* qarow_i = qad + b * SS;
    const int jchunk = v / 50;
    const int wslot  = jchunk * 52 + (v - jchunk * 50);

    for (int t = 0; t < SS; ++t) {
        const int q  = __builtin_amdgcn_readfirstlane(qrow_i[t]);
        const int qa = __builtin_amdgcn_readfirstlane(qarow_i[t]);
        const float* wrow = Wtab + q * MEMN;

        u32 ea = 0;
        if (v < VD) ea = EA[(size_t)qa * VD + v];
        float ev = bfu16_to_f((u16)(ea & 0xffffu));
        float av = bfu16_to_f((u16)(ea >> 16));

        if (v < VD) {
            float rd0 = 0.f, rd1 = 0.f;
            #pragma unroll
            for (int m = 0; m < MEMN; m += 2) {
                float wm0 = wrow[m], wm1 = wrow[m + 1];
                rd0 = fmaf(wm0, mv[m], rd0);
                mv[m] = fmaf(wm0, fmaf(-ev, mv[m], av), mv[m]);
                rd1 = fmaf(wm1, mv[m + 1], rd1);
                mv[m + 1] = fmaf(wm1, fmaf(-ev, mv[m + 1], av), mv[m + 1]);
            }
            read_lds[wslot] = rd0 + rd1;
        }
        __syncthreads();

        float part = 0.f;
        {
            const float* rlc = read_lds + wv * 52;
            #pragma unroll
            for (int i = 0; i < 48; i += 4) {
                float4 x = *(const float4*)(rlc + i);
                part = fmaf(x.x, w1r[i],     part);
                part = fmaf(x.y, w1r[i + 1], part);
                part = fmaf(x.z, w1r[i + 2], part);
                part = fmaf(x.w, w1r[i + 3], part);
            }
            part = fmaf(rlc[48], w1r[48], part);
            part = fmaf(rlc[49], w1r[49], part);
        }
        if (lane < FC) part_lds[wv * 52 + lane] = part;
        __syncthreads();

        if (wv == 0) {
            float pf = 0.f;
            if (lane < FC) {
                float h = part_lds[lane] + part_lds[52 + lane] +
                          part_lds[104 + lane] + part_lds[156 + lane] +
                          Q1tab[q * FC + lane];
                pf = fast_tanh(h) * w2f;
            }
            #pragma unroll
            for (int off = 32; off >= 1; off >>= 1) pf += __shfl_xor(pf, off, 64);
            if (lane == 0) out[b * SS + t] = fast_sigmoid(pf + b2f);
        }
    }
}

extern "C" void kernel_launch(void* const* d_in, const int* in_sizes, int n_in,
                              void* d_out, int out_size, void* d_ws, size_t ws_size,
                              hipStream_t stream) {
    const int* qd  = (const int*)d_in[0];
    const int* qad = (const int*)d_in[1];
    const float* qemb  = (const float*)d_in[2];
    const float* qaemb = (const float*)d_in[3];
    const float* km    = (const float*)d_in[4];
    const float* ivm   = (const float*)d_in[5];
    const float* ew    = (const float*)d_in[6];
    const float* eb    = (const float*)d_in[7];
    const float* aw    = (const float*)d_in[8];
    const float* ab    = (const float*)d_in[9];
    const float* w1    = (const float*)d_in[10];
    const float* b1    = (const float*)d_in[11];
    const float* w2    = (const float*)d_in[12];
    const float* b2    = (const float*)d_in[13];
    float* out = (float*)d_out;
    (void)in_sizes; (void)n_in; (void)out_size;

    char* ws = (char*)d_ws;
    float* Wt  = (float*)(ws);                       // 1,000,200 -> pad 1,000,448
    float* Q1  = (float*)(ws + 1000448);             // 1,000,200 -> pad 1,000,448
    u32*   EA  = (u32*)  (ws + 2000896);             // 8,000,800 -> pad 8,001,024
    u16*   W1s = (u16*)  (ws + 10001920);            // 28,672    -> pad 32,768
    u32*   Wh  = (u32*)  (ws + 10034688);            // 5001*28*4=560,112 -> pad 560,640
    u16*   RD  = (u16*)  (ws + 10595328);            // 163,840,000
    const size_t need = 10595328ull + 163840000ull + 512ull;

    hipMemsetAsync(out + (size_t)BB * SS, 0, (size_t)3 * BB * SS * sizeof(float), stream);

    build_wq<<<NQ1, 64, 0, stream>>>(qemb, km, w1, b1, Wt, Wh, Q1);
    build_ea<<<(NQA + EA_R - 1) / EA_R, 256, 0, stream>>>(qaemb, ew, eb, aw, ab, EA);

    if (ws_size >= need) {
        pack_w1<<<56, 256, 0, stream>>>(w1, W1s);
        dkvmn_state<<<BB, 256, 0, stream>>>(qd, qad, Wh, EA, ivm, RD);
        mlp_pred<<<(BB * SS) / 64, 256, 0, stream>>>(RD, qd, Q1, W1s, w2, b2, out);
    } else {
        dkvmn_main<<<BB, 256, 0, stream>>>(qd, qad, Wt, Q1, EA, ivm, w1, w2, b2, out);
    }
}

// Round 14
// 467.997 us; speedup vs baseline: 1.2164x; 1.2164x over previous
//
#include <hip/hip_runtime.h>
#include <hip/hip_fp16.h>

// DKVMN forward, v14 — exact R12 compute + dispatch consolidation.
//  R13 post-mortem: forced v_pk_fma_f16 asm REGRESSED (issue 255->330us; "v"
//  constraints force s->v movs of wrow + block scheduling). With R6 (pk-f32
//  neutral) and R12 (hfma2 neutral): no packed-math 2x exists for this
//  recurrence at HIP level. State's R12 form (~335us) is the structural floor.
//  Residual: ~80us of inter-dispatch gaps (6 dispatches). v14 merges
//  build_wq+build_ea+pack_w1+aux-zeroing into ONE role-dispatched prep kernel.
//  k1 prep : blocks 0..625 EA | 626..1876 WQ (4 q/block) | 1877..1884 pack;
//            all blocks zero a slice of outputs 1..3.
//  k2 dkvmn_state: exact R12 (barrier-free, 256 thr, hfma2 f16 mv, SGPR Wh
//      pairs, EA depth-2 prefetch, RD bf16).
//  k3 mlp_pred : MFMA 16x16x32 bf16 GEMM [B*S,224]@[224,64] + fused epilogue.
// Workspace: Wt 1MB | Q1 1MB | EA 8MB | W1s 32KB | Wh 0.6MB | RD 164MB.

#define NQ1   5001
#define NQA   10001
#define MEMN  50
#define KD    50
#define VD    200
#define FC    50
#define BB    2048
#define SS    200
#define EA_R  16
#define WHS   28       // Wh row stride in u32 (25 pairs + 3 pad, 112B)

#define EA_B   626     // ceil(10001/16)
#define WQ_B   1251    // ceil(5001/4)
#define PACK_B 8
#define PREP_G (EA_B + WQ_B + PACK_B)   // 1885 blocks

typedef unsigned int   u32;
typedef unsigned short u16;
typedef short  s8v  __attribute__((ext_vector_type(8)));   // 8 bf16 (4 VGPRs)
typedef float  f4v  __attribute__((ext_vector_type(4)));   // MFMA C/D

__device__ __forceinline__ float fast_sigmoid(float x) { return 1.f / (1.f + __expf(-x)); }
__device__ __forceinline__ float fast_tanh(float x) {
    float e2 = __expf(2.f * x);           // inf-safe
    return 1.f - 2.f / (e2 + 1.f);
}
__device__ __forceinline__ float bfu16_to_f(u16 u) {
    union { float f; u32 i; } x; x.i = ((u32)u) << 16; return x.f;
}
__device__ __forceinline__ u16 f_to_bfu16(float f) {   // RNE, finite inputs
    union { float f; u32 i; } x; x.f = f;
    return (u16)((x.i + 0x7fffu + ((x.i >> 16) & 1u)) >> 16);
}
__device__ __forceinline__ __half2 u32_to_h2(u32 u) {
    union { u32 i; __half2 h; } x; x.i = u; return x.h;
}
__device__ __forceinline__ u32 h2_to_u32(__half2 h) {
    union { __half2 h; u32 i; } x; x.h = h; return x.i;
}

// ---- merged prep: EA table | per-q tables | W1 pack | aux-output zeroing ----
__global__ __launch_bounds__(256) void prep(
        const float* __restrict__ qemb, const float* __restrict__ km,
        const float* __restrict__ w1,   const float* __restrict__ b1,
        const float* __restrict__ qaemb,
        const float* __restrict__ ew,   const float* __restrict__ ebias,
        const float* __restrict__ aw,   const float* __restrict__ abias,
        float* __restrict__ Wt, u32* __restrict__ Wh, float* __restrict__ Q1,
        u32* __restrict__ EA, u16* __restrict__ W1s,
        float* __restrict__ out_aux) {
    const int tid = threadIdx.x;
    const int blk = blockIdx.x;

    // every block zeroes its slice of outputs 1..3 (replaces hipMemsetAsync)
    for (size_t i = (size_t)blk * 256 + tid; i < 3ull * BB * SS;
         i += (size_t)PREP_G * 256)
        out_aux[i] = 0.f;

    __shared__ float smem[VD * EA_R];             // 12.8 KB (EA role); WQ uses 256

    if (blk < EA_B) {
        // ---------------- EA role (== proven build_ea) ----------------
        const int r0 = blk * EA_R;
        if (tid < VD) {
            #pragma unroll
            for (int r = 0; r < EA_R; ++r) {
                int row = r0 + r;
                smem[tid * EA_R + r] = (row < NQA) ? qaemb[(size_t)row * VD + tid] : 0.f;
            }
        }
        __syncthreads();
        if (tid >= VD) return;

        float accE[EA_R], accA[EA_R];
        #pragma unroll
        for (int r = 0; r < EA_R; ++r) { accE[r] = 0.f; accA[r] = 0.f; }
        for (int k = 0; k < VD; ++k) {
            float we = ew[k * VD + tid];
            float wa = aw[k * VD + tid];
            #pragma unroll
            for (int r = 0; r < EA_R; ++r) {
                float qv = smem[k * EA_R + r];
                accE[r] = fmaf(qv, we, accE[r]);
                accA[r] = fmaf(qv, wa, accA[r]);
            }
        }
        float be = ebias[tid], ba = abias[tid];
        #pragma unroll
        for (int r = 0; r < EA_R; ++r) {
            int row = r0 + r;
            if (row < NQA) {
                u16 e16 = f_to_bfu16(fast_sigmoid(accE[r] + be));
                u16 a16 = f_to_bfu16(fast_tanh(accA[r] + ba));
                EA[(size_t)row * VD + tid] = (u32)e16 | ((u32)a16 << 16);
            }
        }
    } else if (blk < EA_B + WQ_B) {
        // ---------------- WQ role (== proven build_wq, 4 q/block) ----------------
        const int lane = tid & 63;
        const int wv   = tid >> 6;
        const int q    = (blk - EA_B) * 4 + wv;
        const bool qok = q < NQ1;
        float* qrow = smem + wv * 64;             // 50 used per wave
        if (qok && lane < KD) qrow[lane] = qemb[q * KD + lane];
        __syncthreads();
        if (!qok) return;

        float s = -1e30f;
        if (lane < MEMN) {
            s = 0.f;
            #pragma unroll
            for (int k = 0; k < KD; ++k) s = fmaf(qrow[k], km[lane * KD + k], s);
        }
        float mx = s;
        #pragma unroll
        for (int off = 32; off >= 1; off >>= 1) mx = fmaxf(mx, __shfl_xor(mx, off, 64));
        float e = (lane < MEMN) ? __expf(s - mx) : 0.f;
        float sum = e;
        #pragma unroll
        for (int off = 32; off >= 1; off >>= 1) sum += __shfl_xor(sum, off, 64);
        float wv_ = (lane < MEMN) ? (e / sum) : 0.f;
        if (lane < MEMN) Wt[q * MEMN + lane] = wv_;

        // f16-pair row: lane i<25 packs (w[2i], w[2i+1])
        float plo = __shfl(wv_, 2 * (lane & 31), 64);
        float phi = __shfl(wv_, 2 * (lane & 31) + 1, 64);
        if (lane < 25) {
            union { __half h; u16 u; } lo, hi;
            lo.h = __float2half(plo); hi.h = __float2half(phi);
            Wh[q * WHS + lane] = (u32)lo.u | ((u32)hi.u << 16);
        } else if (lane < WHS) {
            Wh[q * WHS + lane] = 0;
        }

        if (lane < FC) {
            float h = b1[lane];
            #pragma unroll
            for (int k = 0; k < KD; ++k)
                h = fmaf(qrow[k], w1[(VD + k) * FC + lane], h);
            Q1[q * FC + lane] = h;
        }
    } else {
        // ---------------- pack role (== proven pack_w1) ----------------
        for (int idx = (blk - EA_B - WQ_B) * 256 + tid; idx < 4 * 7 * 64 * 8;
             idx += PACK_B * 256) {
            int j    = idx & 7;
            int lane = (idx >> 3) & 63;
            int kt   = (idx >> 9) % 7;
            int nt   = idx / 3584;
            int k = kt * 32 + ((lane >> 4) << 3) + j;
            int n = nt * 16 + (lane & 15);
            float v = (k < VD && n < FC) ? w1[k * FC + n] : 0.f;
            W1s[idx] = f_to_bfu16(v);
        }
    }
}

// ---- recurrence: exact R12 (256 thr, hfma2 f16, SGPR w pairs, EA depth-2) ----
__global__ __launch_bounds__(256) void dkvmn_state(
        const int* __restrict__ qd, const int* __restrict__ qad,
        const u32* __restrict__ Wh, const u32* __restrict__ EA,
        const float* __restrict__ ivm, u16* __restrict__ READ) {
    const int tid = threadIdx.x;
    const int b   = blockIdx.x;
    const int v   = tid;                         // 0..255, active if < VD
    const bool active = v < VD;
    const int vc = active ? v : VD - 1;

    __half2 mv[25];                              // pair i = slots (2i, 2i+1)
    #pragma unroll
    for (int i = 0; i < 25; ++i)
        mv[i] = __floats2half2_rn(ivm[(2 * i) * VD + vc],
                                  ivm[(2 * i + 1) * VD + vc]);

    const int base = b * SS;
    int q_c = __builtin_amdgcn_readfirstlane(qd[base]);
    int q_n = __builtin_amdgcn_readfirstlane(qd[base + 1]);
    int qa0 = __builtin_amdgcn_readfirstlane(qad[base]);
    int qa1 = __builtin_amdgcn_readfirstlane(qad[base + 1]);
    u32 ea_c = EA[(size_t)qa0 * VD + vc];
    u32 ea_n = EA[(size_t)qa1 * VD + vc];

    for (int t = 0; t < SS; ++t) {
        // prefetch step t+2 (clamped index; duplicate load harmless)
        int tn = t + 2; tn = (tn < SS) ? tn : (SS - 1);
        int q_nn  = __builtin_amdgcn_readfirstlane(qd[base + tn]);
        int qa_nn = __builtin_amdgcn_readfirstlane(qad[base + tn]);
        u32 ea_nn = EA[(size_t)qa_nn * VD + vc];

        const u32* wrow = Wh + q_c * WHS;        // uniform -> s_load clause
        float ev = bfu16_to_f((u16)(ea_c & 0xffffu));
        float av = bfu16_to_f((u16)(ea_c >> 16));
        __half2 av2 = __float2half2_rn(av);
        __half2 nev2 = __float2half2_rn(-ev);

        __half2 rdA = __float2half2_rn(0.f), rdB = __float2half2_rn(0.f);
        #pragma unroll
        for (int i = 0; i < 25; i += 2) {        // 13 iters (i=24 single)
            __half2 w0 = u32_to_h2(wrow[i]);
            rdA = __hfma2(w0, mv[i], rdA);
            mv[i] = __hfma2(w0, __hfma2(nev2, mv[i], av2), mv[i]);
            if (i + 1 < 25) {
                __half2 w1p = u32_to_h2(wrow[i + 1]);
                rdB = __hfma2(w1p, mv[i + 1], rdB);
                mv[i + 1] = __hfma2(w1p, __hfma2(nev2, mv[i + 1], av2), mv[i + 1]);
            }
        }
        if (active) {
            __half2 s2 = __hadd2(rdA, rdB);
            float rd = __half2float(__low2half(s2)) + __half2float(__high2half(s2));
            READ[(size_t)(base + t) * VD + v] = f_to_bfu16(rd);
        }
        q_c = q_n; q_n = q_nn; ea_c = ea_n; ea_n = ea_nn;
    }
}

// ---- prediction MLP via MFMA: per wave one 16-row strip, K=224, N=64 ----
__global__ __launch_bounds__(256) void mlp_pred(
        const u16* __restrict__ RD, const int* __restrict__ qd,
        const float* __restrict__ Q1tab, const u16* __restrict__ W1s,
        const float* __restrict__ w2, const float* __restrict__ b2,
        float* __restrict__ out) {
    const int tid  = threadIdx.x;
    const int lane = tid & 63;
    const int wv   = tid >> 6;
    const int strip = blockIdx.x * 4 + wv;
    const int row0  = strip * 16;

    const int mrow = lane & 15;        // A row within strip / C-D col (feature)
    const int quad = lane >> 4;

    s8v a[7];
    {
        const u16* arow = RD + (size_t)(row0 + mrow) * VD + quad * 8;
        #pragma unroll
        for (int kt = 0; kt < 7; ++kt)
            a[kt] = *(const s8v*)(arow + kt * 32);   // k>=200 garbage * B=0
    }

    const float b2f = b2[0];
    float pf[4] = {0.f, 0.f, 0.f, 0.f};

    #pragma unroll
    for (int nt = 0; nt < 4; ++nt) {
        s8v bfr[7];
        #pragma unroll
        for (int kt = 0; kt < 7; ++kt)
            bfr[kt] = *(const s8v*)(W1s + (((nt * 7 + kt) * 64) + lane) * 8);

        f4v acc = {0.f, 0.f, 0.f, 0.f};
        #pragma unroll
        for (int kt = 0; kt < 7; ++kt)
            acc = __builtin_amdgcn_mfma_f32_16x16x32_bf16(a[kt], bfr[kt], acc, 0, 0, 0);

        const int f = nt * 16 + mrow;                  // output feature col
        const float w2f = (f < FC) ? w2[f] : 0.f;
        #pragma unroll
        for (int r = 0; r < 4; ++r) {
            int row = row0 + quad * 4 + r;
            float h = acc[r] + Q1tab[qd[row] * FC + f];
            pf[r] = fmaf(fast_tanh(h), w2f, pf[r]);
        }
    }

    #pragma unroll
    for (int r = 0; r < 4; ++r) {
        float s = pf[r];
        s += __shfl_xor(s, 1, 64);
        s += __shfl_xor(s, 2, 64);
        s += __shfl_xor(s, 4, 64);
        s += __shfl_xor(s, 8, 64);
        if (mrow == 0)
            out[row0 + quad * 4 + r] = fast_sigmoid(s + b2f);
    }
}

// ---- fallback (barrier version, f32) if workspace too small ----
__global__ void dkvmn_main(const int* __restrict__ qd, const int* __restrict__ qad,
                           const float* __restrict__ Wtab, const float* __restrict__ Q1tab,
                           const u32* __restrict__ EA,
                           const float* __restrict__ ivm,
                           const float* __restrict__ w1,
                           const float* __restrict__ w2,
                           const float* __restrict__ b2,
                           float* __restrict__ out) {
    const int tid  = threadIdx.x;
    const int b    = blockIdx.x;
    const int v    = tid;
    const int lane = tid & 63;
    const int wv   = tid >> 6;

    __shared__ alignas(16) float read_lds[4 * 52];
    __shared__ alignas(16) float part_lds[4 * 52];

    float mv[MEMN];
    if (v < VD) {
        #pragma unroll
        for (int m = 0; m < MEMN; ++m) mv[m] = ivm[m * VD + v];
    }
    float w1r[50];
    if (lane < FC) {
        #pragma unroll
        for (int i = 0; i < 50; ++i) w1r[i] = w1[(wv * 50 + i) * FC + lane];
    } else {
        #pragma unroll
        for (int i = 0; i < 50; ++i) w1r[i] = 0.f;
    }
    const float w2f = (tid < FC) ? w2[tid] : 0.f;
    const float b2f = b2[0];

    const int* qrow_i  = qd  + b * SS;
    const int* qarow_i = qad + b * SS;
    const int jchunk = v / 50;
    const int wslot  = jchunk * 52 + (v - jchunk * 50);

    for (int t = 0; t < SS; ++t) {
        const int q  = __builtin_amdgcn_readfirstlane(qrow_i[t]);
        const int qa = __builtin_amdgcn_readfirstlane(qarow_i[t]);
        const float* wrow = Wtab + q * MEMN;

        u32 ea = 0;
        if (v < VD) ea = EA[(size_t)qa * VD + v];
        float ev = bfu16_to_f((u16)(ea & 0xffffu));
        float av = bfu16_to_f((u16)(ea >> 16));

        if (v < VD) {
            float rd0 = 0.f, rd1 = 0.f;
            #pragma unroll
            for (int m = 0; m < MEMN; m += 2) {
                float wm0 = wrow[m], wm1 = wrow[m + 1];
                rd0 = fmaf(wm0, mv[m], rd0);
                mv[m] = fmaf(wm0, fmaf(-ev, mv[m], av), mv[m]);
                rd1 = fmaf(wm1, mv[m + 1], rd1);
                mv[m + 1] = fmaf(wm1, fmaf(-ev, mv[m + 1], av), mv[m + 1]);
            }
            read_lds[wslot] = rd0 + rd1;
        }
        __syncthreads();

        float part = 0.f;
        {
            const float* rlc = read_lds + wv * 52;
            #pragma unroll
            for (int i = 0; i < 48; i += 4) {
                float4 x = *(const float4*)(rlc + i);
                part = fmaf(x.x, w1r[i],     part);
                part = fmaf(x.y, w1r[i + 1], part);
                part = fmaf(x.z, w1r[i + 2], part);
                part = fmaf(x.w, w1r[i + 3], part);
            }
            part = fmaf(rlc[48], w1r[48], part);
            part = fmaf(rlc[49], w1r[49], part);
        }
        if (lane < FC) part_lds[wv * 52 + lane] = part;
        __syncthreads();

        if (wv == 0) {
            float pf = 0.f;
            if (lane < FC) {
                float h = part_lds[lane] + part_lds[52 + lane] +
                          part_lds[104 + lane] + part_lds[156 + lane] +
                          Q1tab[q * FC + lane];
                pf = fast_tanh(h) * w2f;
            }
            #pragma unroll
            for (int off = 32; off >= 1; off >>= 1) pf += __shfl_xor(pf, off, 64);
            if (lane == 0) out[b * SS + t] = fast_sigmoid(pf + b2f);
        }
    }
}

extern "C" void kernel_launch(void* const* d_in, const int* in_sizes, int n_in,
                              void* d_out, int out_size, void* d_ws, size_t ws_size,
                              hipStream_t stream) {
    const int* qd  = (const int*)d_in[0];
    const int* qad = (const int*)d_in[1];
    const float* qemb  = (const float*)d_in[2];
    const float* qaemb = (const float*)d_in[3];
    const float* km    = (const float*)d_in[4];
    const float* ivm   = (const float*)d_in[5];
    const float* ew    = (const float*)d_in[6];
    const float* eb    = (const float*)d_in[7];
    const float* aw    = (const float*)d_in[8];
    const float* ab    = (const float*)d_in[9];
    const float* w1    = (const float*)d_in[10];
    const float* b1    = (const float*)d_in[11];
    const float* w2    = (const float*)d_in[12];
    const float* b2    = (const float*)d_in[13];
    float* out = (float*)d_out;
    (void)in_sizes; (void)n_in; (void)out_size;

    char* ws = (char*)d_ws;
    float* Wt  = (float*)(ws);                       // 1,000,200 -> pad 1,000,448
    float* Q1  = (float*)(ws + 1000448);             // 1,000,200 -> pad 1,000,448
    u32*   EA  = (u32*)  (ws + 2000896);             // 8,000,800 -> pad 8,001,024
    u16*   W1s = (u16*)  (ws + 10001920);            // 28,672    -> pad 32,768
    u32*   Wh  = (u32*)  (ws + 10034688);            // 560,112   -> pad 560,640
    u16*   RD  = (u16*)  (ws + 10595328);            // 163,840,000
    const size_t need = 10595328ull + 163840000ull + 512ull;

    // prep: EA + Wt/Wh/Q1 + W1s + zero outputs 1..3 (one dispatch)
    prep<<<PREP_G, 256, 0, stream>>>(qemb, km, w1, b1, qaemb, ew, eb, aw, ab,
                                     Wt, Wh, Q1, EA, W1s, out + (size_t)BB * SS);

    if (ws_size >= need) {
        dkvmn_state<<<BB, 256, 0, stream>>>(qd, qad, Wh, EA, ivm, RD);
        mlp_pred<<<(BB * SS) / 64, 256, 0, stream>>>(RD, qd, Q1, W1s, w2, b2, out);
    } else {
        dkvmn_main<<<BB, 256, 0, stream>>>(qd, qad, Wt, Q1, EA, ivm, w1, w2, b2, out);
    }
}

// Round 15
// 462.435 us; speedup vs baseline: 1.2310x; 1.0120x over previous
//
#include <hip/hip_runtime.h>
#include <hip/hip_fp16.h>

// DKVMN forward, v15 — cut state inner-loop issue: fdot2 read + f16 EA unpack.
//  Calibrated model (R11-R14): state = 8 waves/SIMD x ~382cyc/step serialized
//  issue (255us) + ~80us all-wave stalls. VOP3P f16 fma measured half-rate
//  (R12 hfma2 == scalar f32). This round: (1) read reduction via
//  v_dot2_f32_f16 (full-rate f32-accum dot, 25 insts vs 50-equiv), (2) EA
//  stored as pre-negated f16 {-e,a} + v_perm broadcasts (2 insts vs 7 unpack),
//  (3) f32 read accumulators (kills f16 tail, better precision).
//  k1 prep : blocks 0..625 EA | 626..1876 WQ (4 q/block) | 1877..1884 pack;
//            all blocks zero a slice of outputs 1..3.
//  k2 dkvmn_state: barrier-free, 256 thr, hfma2 update + fdot2 read, SGPR Wh
//      pairs, EA depth-2 prefetch, RD bf16.
//  k3 mlp_pred : MFMA 16x16x32 bf16 GEMM [B*S,224]@[224,64] + fused epilogue.
// Workspace: Wt 1MB | Q1 1MB | EA 8MB | W1s 32KB | Wh 0.6MB | RD 164MB.

#define NQ1   5001
#define NQA   10001
#define MEMN  50
#define KD    50
#define VD    200
#define FC    50
#define BB    2048
#define SS    200
#define EA_R  16
#define WHS   28       // Wh row stride in u32 (25 pairs + 3 pad, 112B)

#define EA_B   626     // ceil(10001/16)
#define WQ_B   1251    // ceil(5001/4)
#define PACK_B 8
#define PREP_G (EA_B + WQ_B + PACK_B)   // 1885 blocks

typedef unsigned int   u32;
typedef unsigned short u16;
typedef short    s8v __attribute__((ext_vector_type(8)));   // 8 bf16 (4 VGPRs)
typedef float    f4v __attribute__((ext_vector_type(4)));   // MFMA C/D
typedef _Float16 h2v __attribute__((ext_vector_type(2)));   // packed f16 pair

__device__ __forceinline__ float fast_sigmoid(float x) { return 1.f / (1.f + __expf(-x)); }
__device__ __forceinline__ float fast_tanh(float x) {
    float e2 = __expf(2.f * x);           // inf-safe
    return 1.f - 2.f / (e2 + 1.f);
}
__device__ __forceinline__ float bfu16_to_f(u16 u) {
    union { float f; u32 i; } x; x.i = ((u32)u) << 16; return x.f;
}
__device__ __forceinline__ u16 f_to_bfu16(float f) {   // RNE, finite inputs
    union { float f; u32 i; } x; x.f = f;
    return (u16)((x.i + 0x7fffu + ((x.i >> 16) & 1u)) >> 16);
}
__device__ __forceinline__ h2v u32_to_h2v(u32 u) {
    union { u32 i; h2v h; } x; x.i = u; return x.h;
}
__device__ __forceinline__ u16 f16bits(float f) {
    union { __half h; u16 u; } x; x.h = __float2half(f); return x.u;
}
__device__ __forceinline__ float h16_to_f(u16 u) {
    union { u16 u; __half h; } x; x.u = u; return __half2float(x.h);
}

// ---- merged prep: EA table | per-q tables | W1 pack | aux-output zeroing ----
__global__ __launch_bounds__(256) void prep(
        const float* __restrict__ qemb, const float* __restrict__ km,
        const float* __restrict__ w1,   const float* __restrict__ b1,
        const float* __restrict__ qaemb,
        const float* __restrict__ ew,   const float* __restrict__ ebias,
        const float* __restrict__ aw,   const float* __restrict__ abias,
        float* __restrict__ Wt, u32* __restrict__ Wh, float* __restrict__ Q1,
        u32* __restrict__ EA, u16* __restrict__ W1s,
        float* __restrict__ out_aux) {
    const int tid = threadIdx.x;
    const int blk = blockIdx.x;

    // every block zeroes its slice of outputs 1..3 (replaces hipMemsetAsync)
    for (size_t i = (size_t)blk * 256 + tid; i < 3ull * BB * SS;
         i += (size_t)PREP_G * 256)
        out_aux[i] = 0.f;

    __shared__ float smem[VD * EA_R];             // 12.8 KB (EA role); WQ uses 256

    if (blk < EA_B) {
        // ---------------- EA role: {-e, a} packed f16 ----------------
        const int r0 = blk * EA_R;
        if (tid < VD) {
            #pragma unroll
            for (int r = 0; r < EA_R; ++r) {
                int row = r0 + r;
                smem[tid * EA_R + r] = (row < NQA) ? qaemb[(size_t)row * VD + tid] : 0.f;
            }
        }
        __syncthreads();
        if (tid >= VD) return;

        float accE[EA_R], accA[EA_R];
        #pragma unroll
        for (int r = 0; r < EA_R; ++r) { accE[r] = 0.f; accA[r] = 0.f; }
        for (int k = 0; k < VD; ++k) {
            float we = ew[k * VD + tid];
            float wa = aw[k * VD + tid];
            #pragma unroll
            for (int r = 0; r < EA_R; ++r) {
                float qv = smem[k * EA_R + r];
                accE[r] = fmaf(qv, we, accE[r]);
                accA[r] = fmaf(qv, wa, accA[r]);
            }
        }
        float be = ebias[tid], ba = abias[tid];
        #pragma unroll
        for (int r = 0; r < EA_R; ++r) {
            int row = r0 + r;
            if (row < NQA) {
                u16 ne16 = f16bits(-fast_sigmoid(accE[r] + be));   // -e
                u16 a16  = f16bits(fast_tanh(accA[r] + ba));       //  a
                EA[(size_t)row * VD + tid] = (u32)ne16 | ((u32)a16 << 16);
            }
        }
    } else if (blk < EA_B + WQ_B) {
        // ---------------- WQ role (== proven build_wq, 4 q/block) ----------------
        const int lane = tid & 63;
        const int wv   = tid >> 6;
        const int q    = (blk - EA_B) * 4 + wv;
        const bool qok = q < NQ1;
        float* qrow = smem + wv * 64;             // 50 used per wave
        if (qok && lane < KD) qrow[lane] = qemb[q * KD + lane];
        __syncthreads();
        if (!qok) return;

        float s = -1e30f;
        if (lane < MEMN) {
            s = 0.f;
            #pragma unroll
            for (int k = 0; k < KD; ++k) s = fmaf(qrow[k], km[lane * KD + k], s);
        }
        float mx = s;
        #pragma unroll
        for (int off = 32; off >= 1; off >>= 1) mx = fmaxf(mx, __shfl_xor(mx, off, 64));
        float e = (lane < MEMN) ? __expf(s - mx) : 0.f;
        float sum = e;
        #pragma unroll
        for (int off = 32; off >= 1; off >>= 1) sum += __shfl_xor(sum, off, 64);
        float wv_ = (lane < MEMN) ? (e / sum) : 0.f;
        if (lane < MEMN) Wt[q * MEMN + lane] = wv_;

        // f16-pair row: lane i<25 packs (w[2i], w[2i+1])
        float plo = __shfl(wv_, 2 * (lane & 31), 64);
        float phi = __shfl(wv_, 2 * (lane & 31) + 1, 64);
        if (lane < 25) {
            Wh[q * WHS + lane] = (u32)f16bits(plo) | ((u32)f16bits(phi) << 16);
        } else if (lane < WHS) {
            Wh[q * WHS + lane] = 0;
        }

        if (lane < FC) {
            float h = b1[lane];
            #pragma unroll
            for (int k = 0; k < KD; ++k)
                h = fmaf(qrow[k], w1[(VD + k) * FC + lane], h);
            Q1[q * FC + lane] = h;
        }
    } else {
        // ---------------- pack role (== proven pack_w1) ----------------
        for (int idx = (blk - EA_B - WQ_B) * 256 + tid; idx < 4 * 7 * 64 * 8;
             idx += PACK_B * 256) {
            int j    = idx & 7;
            int lane = (idx >> 3) & 63;
            int kt   = (idx >> 9) % 7;
            int nt   = idx / 3584;
            int k = kt * 32 + ((lane >> 4) << 3) + j;
            int n = nt * 16 + (lane & 15);
            float v = (k < VD && n < FC) ? w1[k * FC + n] : 0.f;
            W1s[idx] = f_to_bfu16(v);
        }
    }
}

// ---- recurrence: 256 thr, hfma2 update + fdot2 read, perm EA unpack ----
__global__ __launch_bounds__(256) void dkvmn_state(
        const int* __restrict__ qd, const int* __restrict__ qad,
        const u32* __restrict__ Wh, const u32* __restrict__ EA,
        const float* __restrict__ ivm, u16* __restrict__ READ) {
    const int tid = threadIdx.x;
    const int b   = blockIdx.x;
    const int v   = tid;                         // 0..255, active if < VD
    const bool active = v < VD;
    const int vc = active ? v : VD - 1;

    h2v mv[25];                                  // pair i = slots (2i, 2i+1)
    #pragma unroll
    for (int i = 0; i < 25; ++i) {
        mv[i].x = (_Float16)ivm[(2 * i) * VD + vc];
        mv[i].y = (_Float16)ivm[(2 * i + 1) * VD + vc];
    }

    const int base = b * SS;
    int q_c = __builtin_amdgcn_readfirstlane(qd[base]);
    int q_n = __builtin_amdgcn_readfirstlane(qd[base + 1]);
    int qa0 = __builtin_amdgcn_readfirstlane(qad[base]);
    int qa1 = __builtin_amdgcn_readfirstlane(qad[base + 1]);
    u32 ea_c = EA[(size_t)qa0 * VD + vc];
    u32 ea_n = EA[(size_t)qa1 * VD + vc];

    for (int t = 0; t < SS; ++t) {
        // prefetch step t+2 (clamped index; duplicate load harmless)
        int tn = t + 2; tn = (tn < SS) ? tn : (SS - 1);
        int q_nn  = __builtin_amdgcn_readfirstlane(qd[base + tn]);
        int qa_nn = __builtin_amdgcn_readfirstlane(qad[base + tn]);
        u32 ea_nn = EA[(size_t)qa_nn * VD + vc];

        const u32* wrow = Wh + q_c * WHS;        // uniform -> s_load clause
        // ea_c = {-e (lo f16), a (hi f16)}; broadcast halves via v_perm
        h2v nev2 = u32_to_h2v(__builtin_amdgcn_perm(ea_c, ea_c, 0x01000100u));
        h2v av2  = u32_to_h2v(__builtin_amdgcn_perm(ea_c, ea_c, 0x03020302u));

        float rdA = 0.f, rdB = 0.f;
        #pragma unroll
        for (int i = 0; i < 25; i += 2) {        // 13 iters (i=24 single)
            h2v w0 = u32_to_h2v(wrow[i]);
#if __has_builtin(__builtin_amdgcn_fdot2)
            rdA = __builtin_amdgcn_fdot2(w0, mv[i], rdA, false);
#else
            rdA = fmaf((float)w0.x, (float)mv[i].x,
                  fmaf((float)w0.y, (float)mv[i].y, rdA));
#endif
            mv[i] = __builtin_elementwise_fma(
                w0, __builtin_elementwise_fma(nev2, mv[i], av2), mv[i]);
            if (i + 1 < 25) {
                h2v w1p = u32_to_h2v(wrow[i + 1]);
#if __has_builtin(__builtin_amdgcn_fdot2)
                rdB = __builtin_amdgcn_fdot2(w1p, mv[i + 1], rdB, false);
#else
                rdB = fmaf((float)w1p.x, (float)mv[i + 1].x,
                      fmaf((float)w1p.y, (float)mv[i + 1].y, rdB));
#endif
                mv[i + 1] = __builtin_elementwise_fma(
                    w1p, __builtin_elementwise_fma(nev2, mv[i + 1], av2), mv[i + 1]);
            }
        }
        if (active)
            READ[(size_t)(base + t) * VD + v] = f_to_bfu16(rdA + rdB);
        q_c = q_n; q_n = q_nn; ea_c = ea_n; ea_n = ea_nn;
    }
}

// ---- prediction MLP via MFMA: per wave one 16-row strip, K=224, N=64 ----
__global__ __launch_bounds__(256) void mlp_pred(
        const u16* __restrict__ RD, const int* __restrict__ qd,
        const float* __restrict__ Q1tab, const u16* __restrict__ W1s,
        const float* __restrict__ w2, const float* __restrict__ b2,
        float* __restrict__ out) {
    const int tid  = threadIdx.x;
    const int lane = tid & 63;
    const int wv   = tid >> 6;
    const int strip = blockIdx.x * 4 + wv;
    const int row0  = strip * 16;

    const int mrow = lane & 15;        // A row within strip / C-D col (feature)
    const int quad = lane >> 4;

    s8v a[7];
    {
        const u16* arow = RD + (size_t)(row0 + mrow) * VD + quad * 8;
        #pragma unroll
        for (int kt = 0; kt < 7; ++kt)
            a[kt] = *(const s8v*)(arow + kt * 32);   // k>=200 garbage * B=0
    }

    const float b2f = b2[0];
    float pf[4] = {0.f, 0.f, 0.f, 0.f};

    #pragma unroll
    for (int nt = 0; nt < 4; ++nt) {
        s8v bfr[7];
        #pragma unroll
        for (int kt = 0; kt < 7; ++kt)
            bfr[kt] = *(const s8v*)(W1s + (((nt * 7 + kt) * 64) + lane) * 8);

        f4v acc = {0.f, 0.f, 0.f, 0.f};
        #pragma unroll
        for (int kt = 0; kt < 7; ++kt)
            acc = __builtin_amdgcn_mfma_f32_16x16x32_bf16(a[kt], bfr[kt], acc, 0, 0, 0);

        const int f = nt * 16 + mrow;                  // output feature col
        const float w2f = (f < FC) ? w2[f] : 0.f;
        #pragma unroll
        for (int r = 0; r < 4; ++r) {
            int row = row0 + quad * 4 + r;
            float h = acc[r] + Q1tab[qd[row] * FC + f];
            pf[r] = fmaf(fast_tanh(h), w2f, pf[r]);
        }
    }

    #pragma unroll
    for (int r = 0; r < 4; ++r) {
        float s = pf[r];
        s += __shfl_xor(s, 1, 64);
        s += __shfl_xor(s, 2, 64);
        s += __shfl_xor(s, 4, 64);
        s += __shfl_xor(s, 8, 64);
        if (mrow == 0)
            out[row0 + quad * 4 + r] = fast_sigmoid(s + b2f);
    }
}

// ---- fallback (barrier version, f32) if workspace too small ----
__global__ void dkvmn_main(const int* __restrict__ qd, const int* __restrict__ qad,
                           const float* __restrict__ Wtab, const float* __restrict__ Q1tab,
                           const u32* __restrict__ EA,
                           const float* __restrict__ ivm,
                           const float* __restrict__ w1,
                           const float* __restrict__ w2,
                           const float* __restrict__ b2,
                           float* __restrict__ out) {
    const int tid  = threadIdx.x;
    const int b    = blockIdx.x;
    const int v    = tid;
    const int lane = tid & 63;
    const int wv   = tid >> 6;

    __shared__ alignas(16) float read_lds[4 * 52];
    __shared__ alignas(16) float part_lds[4 * 52];

    float mv[MEMN];
    if (v < VD) {
        #pragma unroll
        for (int m = 0; m < MEMN; ++m) mv[m] = ivm[m * VD + v];
    }
    float w1r[50];
    if (lane < FC) {
        #pragma unroll
        for (int i = 0; i < 50; ++i) w1r[i] = w1[(wv * 50 + i) * FC + lane];
    } else {
        #pragma unroll
        for (int i = 0; i < 50; ++i) w1r[i] = 0.f;
    }
    const float w2f = (tid < FC) ? w2[tid] : 0.f;
    const float b2f = b2[0];

    const int* qrow_i  = qd  + b * SS;
    const int* qarow_i = qad + b * SS;
    const int jchunk = v / 50;
    const int wslot  = jchunk * 52 + (v - jchunk * 50);

    for (int t = 0; t < SS; ++t) {
        const int q  = __builtin_amdgcn_readfirstlane(qrow_i[t]);
        const int qa = __builtin_amdgcn_readfirstlane(qarow_i[t]);
        const float* wrow = Wtab + q * MEMN;

        u32 ea = 0;
        if (v < VD) ea = EA[(size_t)qa * VD + v];
        float ne = h16_to_f((u16)(ea & 0xffffu));   // -e
        float av = h16_to_f((u16)(ea >> 16));       //  a

        if (v < VD) {
            float rd0 = 0.f, rd1 = 0.f;
            #pragma unroll
            for (int m = 0; m < MEMN; m += 2) {
                float wm0 = wrow[m], wm1 = wrow[m + 1];
                rd0 = fmaf(wm0, mv[m], rd0);
                mv[m] = fmaf(wm0, fmaf(ne, mv[m], av), mv[m]);
                rd1 = fmaf(wm1, mv[m + 1], rd1);
                mv[m + 1] = fmaf(wm1, fmaf(ne, mv[m + 1], av), mv[m + 1]);
            }
            read_lds[wslot] = rd0 + rd1;
        }
        __syncthreads();

        float part = 0.f;
        {
            const float* rlc = read_lds + wv * 52;
            #pragma unroll
            for (int i = 0; i < 48; i += 4) {
                float4 x = *(const float4*)(rlc + i);
                part = fmaf(x.x, w1r[i],     part);
                part = fmaf(x.y, w1r[i + 1], part);
                part = fmaf(x.z, w1r[i + 2], part);
                part = fmaf(x.w, w1r[i + 3], part);
            }
            part = fmaf(rlc[48], w1r[48], part);
            part = fmaf(rlc[49], w1r[49], part);
        }
        if (lane < FC) part_lds[wv * 52 + lane] = part;
        __syncthreads();

        if (wv == 0) {
            float pf = 0.f;
            if (lane < FC) {
                float h = part_lds[lane] + part_lds[52 + lane] +
                          part_lds[104 + lane] + part_lds[156 + lane] +
                          Q1tab[q * FC + lane];
                pf = fast_tanh(h) * w2f;
            }
            #pragma unroll
            for (int off = 32; off >= 1; off >>= 1) pf += __shfl_xor(pf, off, 64);
            if (lane == 0) out[b * SS + t] = fast_sigmoid(pf + b2f);
        }
    }
}

extern "C" void kernel_launch(void* const* d_in, const int* in_sizes, int n_in,
                              void* d_out, int out_size, void* d_ws, size_t ws_size,
                              hipStream_t stream) {
    const int* qd  = (const int*)d_in[0];
    const int* qad = (const int*)d_in[1];
    const float* qemb  = (const float*)d_in[2];
    const float* qaemb = (const float*)d_in[3];
    const float* km    = (const float*)d_in[4];
    const float* ivm   = (const float*)d_in[5];
    const float* ew    = (const float*)d_in[6];
    const float* eb    = (const float*)d_in[7];
    const float* aw    = (const float*)d_in[8];
    const float* ab    = (const float*)d_in[9];
    const float* w1    = (const float*)d_in[10];
    const float* b1    = (const float*)d_in[11];
    const float* w2    = (const float*)d_in[12];
    const float* b2    = (const float*)d_in[13];
    float* out = (float*)d_out;
    (void)in_sizes; (void)n_in; (void)out_size;

    char* ws = (char*)d_ws;
    float* Wt  = (float*)(ws);                       // 1,000,200 -> pad 1,000,448
    float* Q1  = (float*)(ws + 1000448);             // 1,000,200 -> pad 1,000,448
    u32*   EA  = (u32*)  (ws + 2000896);             // 8,000,800 -> pad 8,001,024
    u16*   W1s = (u16*)  (ws + 10001920);            // 28,672    -> pad 32,768
    u32*   Wh  = (u32*)  (ws + 10034688);            // 560,112   -> pad 560,640
    u16*   RD  = (u16*)  (ws + 10595328);            // 163,840,000
    const size_t need = 10595328ull + 163840000ull + 512ull;

    // prep: EA + Wt/Wh/Q1 + W1s + zero outputs 1..3 (one dispatch)
    prep<<<PREP_G, 256, 0, stream>>>(qemb, km, w1, b1, qaemb, ew, eb, aw, ab,
                                     Wt, Wh, Q1, EA, W1s, out + (size_t)BB * SS);

    if (ws_size >= need) {
        dkvmn_state<<<BB, 256, 0, stream>>>(qd, qad, Wh, EA, ivm, RD);
        mlp_pred<<<(BB * SS) / 64, 256, 0, stream>>>(RD, qd, Q1, W1s, w2, b2, out);
    } else {
        dkvmn_main<<<BB, 256, 0, stream>>>(qd, qad, Wt, Q1, EA, ivm, w1, w2, b2, out);
    }
}